// Round 2
// 379.846 us; speedup vs baseline: 1.0184x; 1.0184x over previous
//
#include <hip/hip_runtime.h>

typedef float f32x4 __attribute__((ext_vector_type(4)));

// ---------------------------------------------------------------------------
// Phase 1: fused 4-way GEMV.
//   su[j] = sum_k pos[k]*U[k][j] + neg[k]*O[k][j]   (under_coeffs minus bias)
//   so[j] = sum_k pos[k]*O[k][j] + neg[k]*U[k][j]   (over_coeffs  minus bias)
// v2: 4 column-streams per thread (cols j0, j0+256, j0+512, j0+768).
//   - 8 independent global loads in flight per k-iteration (MLP)
//   - 8 independent FMA accumulator chains (ILP)
//   - dword loads stay alignment-safe (row stride 4097 floats is 16B-odd)
// Block covers 1024 columns; grid: x = col-tiles, y = K-chunks (32 rows).
// ---------------------------------------------------------------------------
__global__ __launch_bounds__(256) void gemv4(
    const float* __restrict__ U, const float* __restrict__ O,
    const float* __restrict__ pos, const float* __restrict__ neg,
    float* __restrict__ su, float* __restrict__ so,
    int K, int ncols, int rows_per_chunk) {
  const int tid = threadIdx.x;
  const int c0 = blockIdx.x << 10;           // 1024 cols per block
  const int j0 = c0 + tid;
  int k0 = blockIdx.y * rows_per_chunk;
  int k1 = k0 + rows_per_chunk;
  if (k1 > K) k1 = K;

  float au[4] = {0.f, 0.f, 0.f, 0.f};
  float ao[4] = {0.f, 0.f, 0.f, 0.f};

  if (c0 + 1024 <= ncols) {
    // fast path: all 4 streams in range
    const float* Up = U + (size_t)k0 * ncols + j0;
    const float* Op = O + (size_t)k0 * ncols + j0;
#pragma unroll 2
    for (int k = k0; k < k1; ++k) {
      float p = pos[k];                      // uniform -> s_load
      float n = neg[k];
      float a0 = Up[0], a1 = Up[256], a2 = Up[512], a3 = Up[768];
      float b0 = Op[0], b1 = Op[256], b2 = Op[512], b3 = Op[768];
      au[0] = fmaf(p, a0, fmaf(n, b0, au[0]));
      ao[0] = fmaf(p, b0, fmaf(n, a0, ao[0]));
      au[1] = fmaf(p, a1, fmaf(n, b1, au[1]));
      ao[1] = fmaf(p, b1, fmaf(n, a1, ao[1]));
      au[2] = fmaf(p, a2, fmaf(n, b2, au[2]));
      ao[2] = fmaf(p, b2, fmaf(n, a2, ao[2]));
      au[3] = fmaf(p, a3, fmaf(n, b3, au[3]));
      ao[3] = fmaf(p, b3, fmaf(n, a3, ao[3]));
      Up += ncols;
      Op += ncols;
    }
#pragma unroll
    for (int s = 0; s < 4; ++s) {
      atomicAdd(&su[j0 + (s << 8)], au[s]);
      atomicAdd(&so[j0 + (s << 8)], ao[s]);
    }
  } else {
    // tail block: per-stream bounds guard
    const float* Up = U + (size_t)k0 * ncols;
    const float* Op = O + (size_t)k0 * ncols;
    for (int k = k0; k < k1; ++k) {
      float p = pos[k];
      float n = neg[k];
#pragma unroll
      for (int s = 0; s < 4; ++s) {
        int j = j0 + (s << 8);
        if (j < ncols) {
          float a = Up[j];
          float b = Op[j];
          au[s] = fmaf(p, a, fmaf(n, b, au[s]));
          ao[s] = fmaf(p, b, fmaf(n, a, ao[s]));
        }
      }
      Up += ncols;
      Op += ncols;
    }
#pragma unroll
    for (int s = 0; s < 4; ++s) {
      int j = j0 + (s << 8);
      if (j < ncols) {
        atomicAdd(&su[j], au[s]);
        atomicAdd(&so[j], ao[s]);
      }
    }
  }
}

// ---------------------------------------------------------------------------
// Phase 2 (pow2 fast path): fill both output tensors.
// Layout per tensor: (n_vars+1) blocks of (n_vars rows x 2 cols).
//   element [b][r][c] = 1, except:
//     r==b (b<n_vars): intervals[r][c]
//     r==0           : value *= (coeff[b] + bias)   (applied AFTER diag set)
// One float4 covers rows r0 (even) and r0+1 of one block (2*n_vars % 4 == 0).
// v3: nontemporal stores via native clang vector type (ext_vector_type) —
// 268 MB streaming writes >> 32 MB L2, skip write-allocate.
// ---------------------------------------------------------------------------
__global__ __launch_bounds__(256) void fill4(
    const float* __restrict__ intervals,
    const float* __restrict__ su, const float* __restrict__ so,
    const float* __restrict__ bias_p,
    float* __restrict__ outU, float* __restrict__ outO,
    float* __restrict__ degs,
    int n_vars, int shift, int mask, int n4total) {
  int i4 = blockIdx.x * blockDim.x + threadIdx.x;

  // degree vectors: 2*n_vars ones
  if (i4 < 2 * n_vars) degs[i4] = 1.0f;
  if (i4 >= n4total) return;

  int i = i4 << 2;                 // element index
  int blk = i >> shift;            // block index in [0, n_vars]
  int within = i & mask;           // element offset inside block
  int r0 = within >> 1;            // even row; float4 = rows r0, r0+1

  f32x4 base = {1.f, 1.f, 1.f, 1.f};
  if (r0 == blk) {                 // diag at even row (never true for blk==n_vars)
    base.x = intervals[2 * blk];
    base.y = intervals[2 * blk + 1];
  } else if (r0 + 1 == blk) {      // diag at odd row
    base.z = intervals[2 * blk];
    base.w = intervals[2 * blk + 1];
  }

  f32x4 vu = base, vo = base;
  if (r0 == 0) {                   // row 0 of this block: scale by coeffs
    float b = bias_p[0];
    float cu = su[blk] + b;
    float co = so[blk] + b;
    vu.x = base.x * cu; vu.y = base.y * cu;
    vo.x = base.x * co; vo.y = base.y * co;
  }

  __builtin_nontemporal_store(vu, reinterpret_cast<f32x4*>(outU) + i4);
  __builtin_nontemporal_store(vo, reinterpret_cast<f32x4*>(outO) + i4);
}

// ---------------------------------------------------------------------------
// Scalar fallback (general n_vars), grid-stride over S elements.
// ---------------------------------------------------------------------------
__global__ __launch_bounds__(256) void fill_scalar(
    const float* __restrict__ intervals,
    const float* __restrict__ su, const float* __restrict__ so,
    const float* __restrict__ bias_p,
    float* __restrict__ outU, float* __restrict__ outO,
    float* __restrict__ degs,
    int n_vars, long long S) {
  long long tid = (long long)blockIdx.x * blockDim.x + threadIdx.x;
  long long nthreads = (long long)gridDim.x * blockDim.x;
  if (tid < 2 * n_vars) degs[tid] = 1.0f;
  int two_n = 2 * n_vars;
  for (long long i = tid; i < S; i += nthreads) {
    int blk = (int)(i / two_n);
    int within = (int)(i - (long long)blk * two_n);
    int r = within >> 1;
    int c = within & 1;
    float v = 1.f;
    if (r == blk) v = intervals[2 * r + c];
    float vu = v, vo = v;
    if (r == 0) {
      float b = bias_p[0];
      vu = v * (su[blk] + b);
      vo = v * (so[blk] + b);
    }
    outU[i] = vu;
    outO[i] = vo;
  }
}

extern "C" void kernel_launch(void* const* d_in, const int* in_sizes, int n_in,
                              void* d_out, int out_size, void* d_ws, size_t ws_size,
                              hipStream_t stream) {
  const float* U         = (const float*)d_in[0];  // layer_inputs_under (K, n_vars+1)
  const float* O         = (const float*)d_in[1];  // layer_inputs_over  (K, n_vars+1)
  // d_in[2], d_in[3]: degree inputs (unused; outputs are ones)
  const float* intervals = (const float*)d_in[4];  // (n_vars, 2)
  const float* pos       = (const float*)d_in[5];  // (K,)
  const float* neg       = (const float*)d_in[6];  // (K,)
  const float* bias      = (const float*)d_in[7];  // (1,)

  const int n_vars = in_sizes[4] / 2;
  const int K      = in_sizes[5];
  const int ncols  = n_vars + 1;

  float* su = (float*)d_ws;        // (ncols,) partial under coeffs
  float* so = su + ncols;          // (ncols,) partial over coeffs
  (void)hipMemsetAsync(d_ws, 0, (size_t)2 * ncols * sizeof(float), stream);

  // Phase 1: GEMV. 1024 cols/block, 32-row chunks -> ~640 blocks (~10 waves/CU).
  const int rows_per_chunk = 32;
  dim3 ggrid((ncols + 1023) / 1024, (K + rows_per_chunk - 1) / rows_per_chunk);
  gemv4<<<ggrid, 256, 0, stream>>>(U, O, pos, neg, su, so, K, ncols, rows_per_chunk);

  // Phase 2: fill outputs.
  const long long S = (long long)ncols * n_vars * 2;  // elements per ibf tensor
  float* outU = (float*)d_out;
  float* outO = outU + S;
  float* degs = outU + 2 * S;

  const int two_n = 2 * n_vars;
  const bool pow2 = two_n > 0 && (two_n & (two_n - 1)) == 0 && (two_n % 4 == 0);
  if (pow2 && S / 4 < (1LL << 31)) {
    int shift = __builtin_ctz((unsigned)two_n);
    int n4 = (int)(S / 4);
    long long nthreads = n4 > 2 * n_vars ? n4 : 2 * n_vars;
    int blocks = (int)((nthreads + 255) / 256);
    fill4<<<blocks, 256, 0, stream>>>(intervals, su, so, bias, outU, outO, degs,
                                      n_vars, shift, two_n - 1, n4);
  } else {
    int blocks = 4096;
    fill_scalar<<<blocks, 256, 0, stream>>>(intervals, su, so, bias, outU, outO, degs,
                                            n_vars, S);
  }
}